// Round 9
// baseline (225.994 us; speedup 1.0000x reference)
//
#include <hip/hip_runtime.h>
#include <stdint.h>

#define B_ 8
#define N_ 2048
#define D_ 128
#define NT_ 32            // 64-wide k-tiles per batch
#define KT_ 8             // tiles per gemm block (ksplit = 4)
#define TILE_BYTES 16384  // G tile image: 128 d x 64 i x 2B
#define PS_ ((size_t)B_ * N_ * D_)

typedef unsigned short u16;
typedef unsigned int u32;
using f32x4 = __attribute__((ext_vector_type(4))) float;
using bf16x8 = __attribute__((ext_vector_type(8))) short;
using u16x8 = __attribute__((ext_vector_type(8))) u16;

__device__ inline u16 f2bf(float x) {
  u32 u = __float_as_uint(x);
  return (u16)((u + 0x7FFFu + ((u >> 16) & 1u)) >> 16);
}
__device__ inline float bf2f(u16 h) { return __uint_as_float((u32)h << 16); }

__device__ inline void glds16(const void* g, void* l) {
  __builtin_amdgcn_global_load_lds((const __attribute__((address_space(1))) void*)g,
                                   (__attribute__((address_space(3))) void*)l, 16, 0, 0);
}

// ---------------------------------------------------------------------------
// prep2 (256 blocks = 8b x 32 i-tiles): per 64 E-rows compute
//   EW1[i][d] = sum_f E[i][f] * W[d][f]        (fp32 out, used by outlite)
//   G[i][d]   = sum_f E[i][f] * W[d][128+f]    -> bf16 [d][i] swizzled images
// K = 128 (E feature dim) -> kf loop is 4 iterations (R8 bug: was 8).
// ---------------------------------------------------------------------------
__global__ __launch_bounds__(256) void prep2_kernel(const float* __restrict__ E,
                                                    const float* __restrict__ W,
                                                    u16* __restrict__ Gimg,
                                                    float* __restrict__ EW1) {
  __shared__ __align__(16) u16 SH[64 * 128];  // 16KB: E-tile, then reused for G^T
  const int blk = blockIdx.x;
  const int b = blk >> 5;
  const int it = blk & 31;
  const int i0 = it * 64;
  const int t = threadIdx.x;
  const int lane = t & 63;
  const int wave = t >> 6;
  const int lm = lane & 15, lh = lane >> 4;

  // ---- Phase A: E tile -> bf16 LDS [i][k8 ^ (i&7)]
  const float* Eb = E + ((size_t)b * N_ + i0) * D_;
#pragma unroll
  for (int c = 0; c < 4; ++c) {
    const int chunk = c * 256 + t;
    const int i = chunk >> 4;
    const int k8 = chunk & 15;
    f32x4 v0 = *(const f32x4*)(Eb + i * D_ + k8 * 8);
    f32x4 v1 = *(const f32x4*)(Eb + i * D_ + k8 * 8 + 4);
    u16x8 pk;
#pragma unroll
    for (int e = 0; e < 4; ++e) { pk[e] = f2bf(v0[e]); pk[4 + e] = f2bf(v1[e]); }
    *(u16x8*)&SH[i * 128 + ((k8 ^ (i & 7)) << 3)] = pk;
  }
  __syncthreads();

  // ---- Phase B: dual MFMA GEMM over K=128 (W1 and W2 share A-frags)
  const int dbase = wave * 32;
  f32x4 acc1[4][2], accG[4][2];
#pragma unroll
  for (int fm = 0; fm < 4; ++fm)
#pragma unroll
    for (int fn = 0; fn < 2; ++fn) { acc1[fm][fn] = (f32x4)0.0f; accG[fm][fn] = (f32x4)0.0f; }
#pragma unroll
  for (int kf = 0; kf < 4; ++kf) {  // K=128: 4 x 32
    bf16x8 af[4];
#pragma unroll
    for (int fm = 0; fm < 4; ++fm) {
      const int i = fm * 16 + lm;
      af[fm] = *(const bf16x8*)&SH[i * 128 + (((kf * 4 + lh) ^ (i & 7)) << 3)];
    }
#pragma unroll
    for (int fn = 0; fn < 2; ++fn) {
      const int d = dbase + fn * 16 + lm;
      const float* wr = W + d * 256 + kf * 32 + lh * 8;  // max col 127 (W1)
      f32x4 a0 = *(const f32x4*)(wr);
      f32x4 a1 = *(const f32x4*)(wr + 4);
      f32x4 b0 = *(const f32x4*)(wr + 128);  // W2 half: cols 128..255
      f32x4 b1 = *(const f32x4*)(wr + 132);
      u16x8 w1, w2;
#pragma unroll
      for (int e = 0; e < 4; ++e) {
        w1[e] = f2bf(a0[e]); w1[4 + e] = f2bf(a1[e]);
        w2[e] = f2bf(b0[e]); w2[4 + e] = f2bf(b1[e]);
      }
      bf16x8 w1f = *(bf16x8*)&w1;
      bf16x8 w2f = *(bf16x8*)&w2;
#pragma unroll
      for (int fm = 0; fm < 4; ++fm) {
        acc1[fm][fn] = __builtin_amdgcn_mfma_f32_16x16x32_bf16(af[fm], w1f, acc1[fm][fn], 0, 0, 0);
        accG[fm][fn] = __builtin_amdgcn_mfma_f32_16x16x32_bf16(af[fm], w2f, accG[fm][fn], 0, 0, 0);
      }
    }
  }
  // ---- EW1 store (fp32 linear)
  float* EWb = EW1 + ((size_t)b * N_ + i0) * D_;
#pragma unroll
  for (int fm = 0; fm < 4; ++fm)
#pragma unroll
    for (int fn = 0; fn < 2; ++fn)
#pragma unroll
      for (int rr = 0; rr < 4; ++rr)
        EWb[(fm * 16 + lh * 4 + rr) * D_ + dbase + fn * 16 + lm] = acc1[fm][fn][rr];

  // ---- G^T scatter into LDS (swizzled chunks), then image write
  __syncthreads();  // all E reads done; reuse SH as Gt[d][i]
#pragma unroll
  for (int fm = 0; fm < 4; ++fm)
#pragma unroll
    for (int fn = 0; fn < 2; ++fn)
#pragma unroll
      for (int rr = 0; rr < 4; ++rr) {
        const int d = dbase + fn * 16 + lm;
        const int il = fm * 16 + lh * 4 + rr;
        SH[d * 64 + ((((il >> 3) ^ (d & 7)) << 3) | (il & 7))] = f2bf(accG[fm][fn][rr]);
      }
  __syncthreads();
  u16* img = Gimg + ((size_t)b * NT_ + it) * (TILE_BYTES / 2);
  const int d = t >> 1;
  const int swz = (d ^ (d >> 3)) & 7;
#pragma unroll
  for (int gg = 0; gg < 4; ++gg) {
    const int grp = (t & 1) * 4 + gg;
    u16x8 pk = *(const u16x8*)&SH[d * 64 + ((grp ^ (d & 7)) << 3)];
    *(u16x8*)(img + d * 64 + ((grp ^ swz) << 3)) = pk;
  }
}

// ---------------------------------------------------------------------------
// Main GEMM (R7 structure verbatim): Hp[ks][row][d] = sum_{i in quarter}
// C[b][i][j] * G[b][i][d], bf16 out. 1024 blocks = 8b x 32jt x 4ks.
// Depth-2 reg prefetch of C; vmcnt(4) steady, vmcnt(0) in tail steps.
// ---------------------------------------------------------------------------
__global__ __launch_bounds__(256) void gemm_kernel(const float* __restrict__ C,
                                                   const u16* __restrict__ Gimg,
                                                   u16* __restrict__ Hp,
                                                   int* __restrict__ zeros) {
  __shared__ __align__(16) u16 Asw[2][64 * 64];   // 16KB
  __shared__ __align__(16) u16 Bsw[2][128 * 64];  // 32KB
  const int phys = blockIdx.x;
  const int orig = (phys & 7) * 128 + (phys >> 3);  // 128 blocks per XCD = 1 batch
  const int b = orig >> 7;
  const int ks = (orig >> 5) & 3;
  const int jt = orig & 31;
  const int j0 = jt * 64;
  const int t = threadIdx.x;
  const int lane = t & 63;
  const int wave = t >> 6;
  const int wm = wave >> 1, wn = wave & 1;
  const int lm = lane & 15, lh = lane >> 4;
  const int aRow = t >> 4, aCol = t & 15;

  const float* Cb = C + (size_t)b * N_ * N_;
  const char* Bimg = (const char*)(Gimg + (size_t)b * NT_ * (TILE_BYTES / 2));
  int* zb = zeros + b * N_;
  const int g0 = ks * KT_;

  f32x4 acc[2][4];
#pragma unroll
  for (int i = 0; i < 2; ++i)
#pragma unroll
    for (int j = 0; j < 4; ++j) acc[i][j] = (f32x4)0.0f;
  f32x4 av[2][4];  // depth-2 ping-pong; ALL indices literal via macros

#define ISSUE_B(gi, buf)                                                          \
  {                                                                               \
    _Pragma("unroll") for (int s = 0; s < 4; ++s) {                               \
      const int chunk = s * 4 + wave;                                             \
      glds16(Bimg + (size_t)(gi)*TILE_BYTES + chunk * 1024 + lane * 16,           \
             (char*)&Bsw[buf][0] + chunk * 1024);                                 \
    }                                                                             \
  }
#define LOAD_A(gi, slot)                                                          \
  {                                                                               \
    _Pragma("unroll") for (int s = 0; s < 4; ++s) av[slot][s] =                   \
        *(const f32x4*)(Cb + (size_t)((gi)*64 + aRow + 16 * s) * N_ + j0 + aCol * 4); \
  }
#define WRITE_A(gi, buf, slot)                                                    \
  {                                                                               \
    _Pragma("unroll") for (int s = 0; s < 4; ++s) {                               \
      const int i = aRow + 16 * s;                                                \
      f32x4 v = av[slot][s];                                                      \
      int zc = (v[0] == 0.0f) + (v[1] == 0.0f) + (v[2] == 0.0f) + (v[3] == 0.0f);\
      if (__any(zc)) {  /* rare: exact-zero entries in C */                       \
        if (zc) atomicAdd(&zb[(gi)*64 + i], zc);                                  \
      }                                                                           \
      _Pragma("unroll") for (int e = 0; e < 4; ++e) {                             \
        const int jl = aCol * 4 + e;                                              \
        const int sz = (jl ^ (jl >> 3)) & 7;                                      \
        Asw[buf][jl * 64 + (i ^ (sz << 3))] = f2bf(v[e]);                         \
      }                                                                           \
    }                                                                             \
  }
#define MFMA_PHASE(buf)                                                           \
  {                                                                               \
    bf16x8 af[2][2], bfr[4][2];                                                   \
    _Pragma("unroll") for (int fm = 0; fm < 2; ++fm) {                            \
      const int jl = wm * 32 + fm * 16 + lm;                                      \
      const int sz = (jl ^ (jl >> 3)) & 7;                                        \
      _Pragma("unroll") for (int kf = 0; kf < 2; ++kf) {                          \
        const int K8 = kf * 32 + lh * 8;                                          \
        af[fm][kf] = *(const bf16x8*)&Asw[buf][jl * 64 + (K8 ^ (sz << 3))];       \
      }                                                                           \
    }                                                                             \
    _Pragma("unroll") for (int fn = 0; fn < 4; ++fn) {                            \
      const int nl = wn * 64 + fn * 16 + lm;                                      \
      const int sz = (nl ^ (nl >> 3)) & 7;                                        \
      _Pragma("unroll") for (int kf = 0; kf < 2; ++kf) {                          \
        const int K8 = kf * 32 + lh * 8;                                          \
        bfr[fn][kf] = *(const bf16x8*)&Bsw[buf][nl * 64 + (K8 ^ (sz << 3))];      \
      }                                                                           \
    }                                                                             \
    _Pragma("unroll") for (int kf = 0; kf < 2; ++kf)                              \
        _Pragma("unroll") for (int fm = 0; fm < 2; ++fm)                          \
        _Pragma("unroll") for (int fn = 0; fn < 4; ++fn) acc[fm][fn] =            \
        __builtin_amdgcn_mfma_f32_16x16x32_bf16(af[fm][kf], bfr[fn][kf],          \
                                                acc[fm][fn], 0, 0, 0);            \
  }
#define STEP(kt, DOLOAD, VMSTR)                                                   \
  ISSUE_B(g0 + (kt) + 1, ((kt) + 1) & 1);                                         \
  __builtin_amdgcn_sched_barrier(0);                                              \
  MFMA_PHASE((kt) & 1);                                                           \
  __builtin_amdgcn_sched_barrier(0);                                              \
  WRITE_A(g0 + (kt) + 1, ((kt) + 1) & 1, (kt) & 1);                               \
  __builtin_amdgcn_sched_barrier(0);                                              \
  if (DOLOAD) LOAD_A(g0 + (kt) + 3, (kt) & 1);                                    \
  __builtin_amdgcn_sched_barrier(0);                                              \
  asm volatile("s_waitcnt " VMSTR ::: "memory");                                  \
  asm volatile("s_waitcnt lgkmcnt(0)" ::: "memory");                              \
  __builtin_amdgcn_sched_barrier(0);                                              \
  __builtin_amdgcn_s_barrier();                                                   \
  __builtin_amdgcn_sched_barrier(0);

  // ---- prologue: tile g0 staged; av0 <- g0+1, av1 <- g0+2 in flight
  ISSUE_B(g0, 0);
  LOAD_A(g0, 0);
  WRITE_A(g0, 0, 0);  // av consume drains glds(g0) too (prologue only)
  LOAD_A(g0 + 1, 0);
  LOAD_A(g0 + 2, 1);
  asm volatile("s_waitcnt lgkmcnt(0)" ::: "memory");
  __builtin_amdgcn_sched_barrier(0);
  __builtin_amdgcn_s_barrier();
  __builtin_amdgcn_sched_barrier(0);

  STEP(0, 1, "vmcnt(4)")
  STEP(1, 1, "vmcnt(4)")
  STEP(2, 1, "vmcnt(4)")
  STEP(3, 1, "vmcnt(4)")
  STEP(4, 1, "vmcnt(4)")
  STEP(5, 0, "vmcnt(0)")  // no LOAD_A: glds are newest, only vmcnt(0) drains them
  STEP(6, 0, "vmcnt(0)")
  MFMA_PHASE(1)  // tile 7 (staged into buf 1)

  u16* Hb = Hp + (size_t)ks * PS_ + ((size_t)b * N_ + j0) * D_;
#pragma unroll
  for (int fm = 0; fm < 2; ++fm)
#pragma unroll
    for (int fn = 0; fn < 4; ++fn)
#pragma unroll
      for (int r = 0; r < 4; ++r) {
        const int row = wm * 32 + fm * 16 + lh * 4 + r;
        const int col = wn * 64 + fn * 16 + lm;
        Hb[(size_t)row * D_ + col] = f2bf(acc[fm][fn][r]);
      }
#undef ISSUE_B
#undef LOAD_A
#undef WRITE_A
#undef MFMA_PHASE
#undef STEP
}

// ---------------------------------------------------------------------------
// outlite (pure elementwise, ~42MB traffic):
// out[row][d] = relu( EW1[row][d] + (sum_ks Hp)[row][d]/(2048-zeros[row]) + b[d] )
// 1024 blocks x 256 thr; one (row, d8-chunk) per thread.
// ---------------------------------------------------------------------------
__global__ __launch_bounds__(256) void outlite_kernel(const float* __restrict__ EW1,
                                                      const u16* __restrict__ Hp,
                                                      const int* __restrict__ zeros,
                                                      const float* __restrict__ bias,
                                                      float* __restrict__ out) {
  const int idx = blockIdx.x * 256 + threadIdx.x;  // 262144 = 16384 rows x 16 chunks
  const int row = idx >> 4;
  const int d8 = idx & 15;
  const float idg = 1.0f / (2048.0f - (float)zeros[row]);
  const size_t off = (size_t)row * D_ + d8 * 8;
  f32x4 e0 = *(const f32x4*)(EW1 + off);
  f32x4 e1 = *(const f32x4*)(EW1 + off + 4);
  u16x8 h0 = *(const u16x8*)(Hp + 0 * PS_ + off);
  u16x8 h1 = *(const u16x8*)(Hp + 1 * PS_ + off);
  u16x8 h2 = *(const u16x8*)(Hp + 2 * PS_ + off);
  u16x8 h3 = *(const u16x8*)(Hp + 3 * PS_ + off);
  f32x4 b0 = *(const f32x4*)(bias + d8 * 8);
  f32x4 b1 = *(const f32x4*)(bias + d8 * 8 + 4);
  f32x4 r0, r1;
#pragma unroll
  for (int e = 0; e < 4; ++e) {
    float s0 = (bf2f(h0[e]) + bf2f(h1[e])) + (bf2f(h2[e]) + bf2f(h3[e]));
    float s1 = (bf2f(h0[4 + e]) + bf2f(h1[4 + e])) + (bf2f(h2[4 + e]) + bf2f(h3[4 + e]));
    float x0 = e0[e] + s0 * idg + b0[e];
    float x1 = e1[e] + s1 * idg + b1[e];
    r0[e] = x0 > 0.0f ? x0 : 0.0f;
    r1[e] = x1 > 0.0f ? x1 : 0.0f;
  }
  *(f32x4*)(out + off) = r0;
  *(f32x4*)(out + off + 4) = r1;
}

extern "C" void kernel_launch(void* const* d_in, const int* in_sizes, int n_in,
                              void* d_out, int out_size, void* d_ws, size_t ws_size,
                              hipStream_t stream) {
  (void)in_sizes; (void)n_in; (void)out_size; (void)ws_size;
  const float* E = (const float*)d_in[0];
  const float* C = (const float*)d_in[1];
  const float* W = (const float*)d_in[2];
  const float* bias = (const float*)d_in[3];
  float* out = (float*)d_out;

  // ws: zeros int[16K] (64KB) | Gimg bf16 4MB | EW1 fp32 8MB | Hp bf16[4] 16.8MB
  char* ws = (char*)d_ws;
  int* zeros = (int*)ws;
  u16* Gimg = (u16*)(ws + 65536);
  float* EW1 = (float*)(ws + 65536 + 4194304);
  u16* Hp = (u16*)(ws + 65536 + 4194304 + 8388608);

  hipMemsetAsync(zeros, 0, B_ * N_ * sizeof(int), stream);
  hipLaunchKernelGGL(prep2_kernel, dim3(256), dim3(256), 0, stream, E, W, Gimg, EW1);
  hipLaunchKernelGGL(gemm_kernel, dim3(1024), dim3(256), 0, stream, C, Gimg, Hp, zeros);
  hipLaunchKernelGGL(outlite_kernel, dim3(1024), dim3(256), 0, stream, EW1, Hp, zeros, bias, out);
}